// Round 7
// baseline (547.877 us; speedup 1.0000x reference)
//
#include <hip/hip_runtime.h>

// Batched Viterbi decode: B=1024, S=512, T=64.  R6b: register-resident scan.
// Forward var stays distributed in registers (lane n holds fv[n]); the 64-way
// all-gather per step is done with 15 parallel ds_bpermute seeds (fv^(4k),
// addresses precomputed) + two DPP quad-perm levels (xor2=0x4E, xor1=0xB1).
// Transitions live in xor-diagonal register layout d[m] = trans[n][n^m] so the
// matching coefficient for fv[n^m] is a STATIC register index. Value-only max
// (order-invariant fp32 => bit-exact); history streamed to d_ws; backpointers
// recomputed lazily in the fused backtrace (one argmax per step, not 64).
// No LDS round-trip for fv, no __syncthreads anywhere (single-wave blocks).

#define B_ 1024
#define S_ 512
#define T_ 64
#define NEGV -10000.0f

// max over all 64 lanes, broadcast (DPP ladder; verified bit-exact in R5)
__device__ __forceinline__ float wave_max64(float v) {
    int x;
#define DPP_MAX(ctrl, rmask)                                                        \
    x = __builtin_amdgcn_update_dpp(__float_as_int(v), __float_as_int(v),           \
                                    ctrl, rmask, 0xf, false);                       \
    v = fmaxf(v, __int_as_float(x));
    DPP_MAX(0x111, 0xf)   // row_shr:1
    DPP_MAX(0x112, 0xf)   // row_shr:2
    DPP_MAX(0x114, 0xf)   // row_shr:4
    DPP_MAX(0x118, 0xf)   // row_shr:8
    DPP_MAX(0x142, 0xa)   // row_bcast:15
    DPP_MAX(0x143, 0xc)   // row_bcast:31 ; lane63 = global max
#undef DPP_MAX
    return __int_as_float(__builtin_amdgcn_readlane(__float_as_int(v), 63));
}

template <int CTRL>
__device__ __forceinline__ int dpp_i(int src) {
    return __builtin_amdgcn_update_dpp(src, src, CTRL, 0xf, 0xf, false);
}

__global__ __launch_bounds__(64, 1) void viterbi_hist_kernel(
    const float* __restrict__ feats,   // [B, S, T]
    const float* __restrict__ trans,   // [T, T]
    float* __restrict__ out,           // [B + B*S]
    float* __restrict__ hist)          // [B, S, T] scratch
{
    __shared__ float ldsT[T_ * 65];    // transitions, row stride 65 (no conflicts)

    const int b = blockIdx.x;
    const int lane = threadIdx.x;      // forward: lane = tag n; backtrace: lane = prev

    // ---- one-time: xor-diagonal transitions d[m] = trans[lane][lane^m] ----
    float d[T_];
#pragma unroll
    for (int m = 0; m < T_; ++m) d[m] = trans[lane * T_ + (lane ^ m)];
    const float tend = trans[(T_ - 1) * T_ + lane];   // transitions[END][lane]

    // ---- one-time: stage padded transitions to LDS for backtrace ----
#pragma unroll 1
    for (int j = 0; j < T_; ++j) ldsT[j * 65 + lane] = trans[j * T_ + lane];

    // ---- one-time: bpermute byte-addresses for xor seeds 4,8,...,60 ----
    int bpa[16];
#pragma unroll
    for (int k = 1; k < 16; ++k) bpa[k] = (lane ^ (4 * k)) << 2;

    float fv = (lane == T_ - 2) ? 0.0f : NEGV;        // START = T-2

    const float* fb = feats + (size_t)b * S_ * T_ + lane;
    float* hb = hist + (size_t)b * S_ * T_ + lane;

    // feat prefetch ring: one unrolled body (4 steps) ahead
    float fc[4], fn[4];
#pragma unroll
    for (int k = 0; k < 4; ++k) fc[k] = fb[(size_t)k * T_];

    // ---------------- forward scan (value-only, register-resident) ----------------
#pragma unroll 1
    for (int s4 = 0; s4 < S_ / 4; ++s4) {
#pragma unroll
        for (int k = 0; k < 4; ++k) {
            int sp = 4 * s4 + 4 + k;
            sp = (sp < S_) ? sp : (S_ - 1);
            fn[k] = fb[(size_t)sp * T_];
        }

#pragma unroll
        for (int u = 0; u < 4; ++u) {
            const int s = 4 * s4 + u;
            hb[(size_t)s * T_] = fv;          // history entering step s

            const int fvi = __float_as_int(fv);
            int sd[16];
            sd[0] = fvi;
#pragma unroll
            for (int k = 1; k < 16; ++k)
                sd[k] = __builtin_amdgcn_ds_bpermute(bpa[k], fvi);

            float pk[16];
#pragma unroll
            for (int k = 0; k < 16; ++k) {
                const float e0 = __int_as_float(sd[k]);       // fv^(4k)
                const int e2i = dpp_i<0x4E>(sd[k]);           // quad_perm [2,3,0,1]
                const float e2 = __int_as_float(e2i);         // fv^(4k+2)
                const float e1 = __int_as_float(dpp_i<0xB1>(sd[k]));   // fv^(4k+1)
                const float e3 = __int_as_float(dpp_i<0xB1>(e2i));     // fv^(4k+3)
                const float c0 = e0 + d[4 * k];
                const float c1 = e1 + d[4 * k + 1];
                const float c2 = e2 + d[4 * k + 2];
                const float c3 = e3 + d[4 * k + 3];
                pk[k] = fmaxf(fmaxf(c0, c1), fmaxf(c2, c3));
            }
            // reduce 16 partials
            const float q0 = fmaxf(fmaxf(pk[0], pk[1]), fmaxf(pk[2], pk[3]));
            const float q1 = fmaxf(fmaxf(pk[4], pk[5]), fmaxf(pk[6], pk[7]));
            const float q2 = fmaxf(fmaxf(pk[8], pk[9]), fmaxf(pk[10], pk[11]));
            const float q3 = fmaxf(fmaxf(pk[12], pk[13]), fmaxf(pk[14], pk[15]));
            const float BV = fmaxf(fmaxf(q0, q1), fmaxf(q2, q3));

            fv = BV + fc[u];
        }
#pragma unroll
        for (int k = 0; k < 4; ++k) fc[k] = fn[k];
    }

    // ---------------- terminal: max + first-index argmax ----------------
    const float tv = fv + tend;
    const float smax = wave_max64(tv);
    const unsigned long long msk = __ballot(tv == smax);
    int tcur = (int)__builtin_ctzll(msk);       // lowest tag on tie = jnp.argmax
    if (lane == 0) out[b] = smax;

    // ---------------- backtrace: lazy per-step argmax ----------------
    float* outp = out + B_ + (size_t)b * S_;

    float hr[16];
#pragma unroll
    for (int dd = 0; dd < 16; ++dd) hr[dd] = hb[(size_t)(S_ - 1 - dd) * T_];

    int emit = 0;
#pragma unroll 1
    for (int g = 0; g < 32; ++g) {
#pragma unroll
        for (int dd = 0; dd < 16; ++dd) {
            const int idx = 16 * g + dd;
            const int s = S_ - 1 - idx;          // 511..0
            const float h = hr[dd];
            if (idx + 16 < S_)
                hr[dd] = hb[(size_t)(s - 16) * T_];

            const float cnd = h + ldsT[tcur * 65 + lane];   // lane = prev
            const float mx = wave_max64(cnd);
            const unsigned long long mk = __ballot(cnd == mx);

            emit = (lane == (s & 63)) ? tcur : emit;   // emit OLD tag at pos s
            tcur = (int)__builtin_ctzll(mk);           // follow backpointer

            if ((s & 63) == 0) {
                outp[s + lane] = (float)emit;
                emit = 0;
            }
        }
    }
}

// ---------------- fallback (ws too small): R4 full-argmax kernel ----------------
__global__ __launch_bounds__(64, 1) void viterbi_fallback_kernel(
    const float* __restrict__ feats, const float* __restrict__ trans,
    float* __restrict__ out)
{
    __shared__ unsigned int bp[S_ / 4][T_];
    __shared__ __align__(16) float fvbuf[2][T_];

    const int b = blockIdx.x;
    const int lane = threadIdx.x;

    float t[T_];
#pragma unroll
    for (int p = 0; p < T_; p += 4) {
        const float4 v = *reinterpret_cast<const float4*>(trans + lane * T_ + p);
        t[p] = v.x; t[p + 1] = v.y; t[p + 2] = v.z; t[p + 3] = v.w;
    }
    const float tend = trans[(T_ - 1) * T_ + lane];

    float fv = (lane == T_ - 2) ? 0.0f : NEGV;
    fvbuf[0][lane] = fv;

    const float* fb = feats + (size_t)b * S_ * T_ + lane;
    unsigned int pack = 0;

#pragma unroll 4
    for (int s = 0; s < S_; ++s) {
        const float feat = fb[(size_t)s * T_];
        const int rs = s & 1;
        float fvl[T_];
#pragma unroll
        for (int j = 0; j < 16; ++j) {
            const float4 v = *reinterpret_cast<const float4*>(&fvbuf[rs][4 * j]);
            fvl[4 * j] = v.x; fvl[4 * j + 1] = v.y;
            fvl[4 * j + 2] = v.z; fvl[4 * j + 3] = v.w;
        }
        float bv[4]; int bi[4];
#pragma unroll
        for (int g = 0; g < 4; ++g) {
            float bestv = fvl[16 * g] + t[16 * g];
            int besti = 16 * g;
#pragma unroll
            for (int q = 1; q < 16; ++q) {
                const int p = 16 * g + q;
                const float c = fvl[p] + t[p];
                const bool gt = c > bestv;
                besti = gt ? p : besti;
                bestv = gt ? c : bestv;
            }
            bv[g] = bestv; bi[g] = besti;
        }
        float BV = bv[0]; int BI = bi[0];
#pragma unroll
        for (int g = 1; g < 4; ++g) {
            const bool gt = bv[g] > BV;
            BI = gt ? bi[g] : BI;
            BV = gt ? bv[g] : BV;
        }
        fv = BV + feat;
        fvbuf[rs ^ 1][lane] = fv;
        pack |= ((unsigned int)BI) << (8 * (s & 3));
        if ((s & 3) == 3) { bp[s >> 2][lane] = pack; pack = 0; }
    }

    float v = fv + tend;
    int i = lane;
#pragma unroll
    for (int off = 1; off < 64; off <<= 1) {
        const float vo = __shfl_xor(v, off);
        const int io = __shfl_xor(i, off);
        const bool take = (vo > v) || ((vo == v) && (io < i));
        v = take ? vo : v;
        i = take ? io : i;
    }
    int tcur = __builtin_amdgcn_readfirstlane(i);
    if (lane == 0) out[b] = v;

    float* outp = out + B_ + (size_t)b * S_;
#pragma unroll 1
    for (int c = 7; c >= 0; --c) {
        unsigned int wd[16];
#pragma unroll
        for (int j = 0; j < 16; ++j) wd[j] = bp[16 * c + j][lane];
        int emit = 0;
#pragma unroll
        for (int k = 63; k >= 0; --k) {
            emit = (lane == k) ? tcur : emit;
            const int word = __builtin_amdgcn_readlane((int)wd[k >> 2], tcur);
            tcur = (word >> (8 * (k & 3))) & 0xff;
        }
        outp[64 * c + lane] = (float)emit;
    }
}

extern "C" void kernel_launch(void* const* d_in, const int* in_sizes, int n_in,
                              void* d_out, int out_size, void* d_ws, size_t ws_size,
                              hipStream_t stream) {
    const float* feats = (const float*)d_in[0];   // [B*S*T] f32
    const float* trans = (const float*)d_in[1];   // [T*T] f32
    float* out = (float*)d_out;                   // [B + B*S] f32
    const size_t need = (size_t)B_ * S_ * T_ * sizeof(float);   // 128 MiB
    if (ws_size >= need) {
        viterbi_hist_kernel<<<dim3(B_), dim3(T_), 0, stream>>>(
            feats, trans, out, (float*)d_ws);
    } else {
        viterbi_fallback_kernel<<<dim3(B_), dim3(T_), 0, stream>>>(feats, trans, out);
    }
}